// Round 2
// baseline (430.919 us; speedup 1.0000x reference)
//
#include <hip/hip_runtime.h>
#include <hip/hip_bf16.h>
#include <stdint.h>

// AdditiveAttention: B=32, S=4096, H=512, A=256
// d_out = [context: 32*512][attn: 32*4096]  (fp32)
//
// R6: persistent fused kernel (grid 512 = 2 blocks/CU, 4 chunks per block) --
// next chunk's A/B prefetches issue right after the k-loop so the epilogue
// (psum/softmax/phase-2) hides the prologue HBM latency; v_cvt_pk_bf16_f32
// replaces manual f2bf+pack in the staging path (32 -> 4 VALU per k-step).

typedef __attribute__((ext_vector_type(4))) float f32x4;
typedef __attribute__((ext_vector_type(8))) short short8;
typedef __attribute__((ext_vector_type(4))) uint32_t u32x4;

#define B_  32
#define S_  4096
#define H_  512
#define A_  256
#define CHUNKS_ 64   // 4096 / 64 rows per chunk

// ---- workspace layout (bytes) ----
#define WS_WT     0            // bf16 W_enc^T [256][512]   : 262144
#define WS_BIAS   262144       // fp32 [32][256]            : 32768
#define WS_SCORES 294912       // fp32 [32][4096] (exp vals): 524288
#define WS_M      819200       // fp32 [32][64]             : 8192
#define WS_L      827392       // fp32 [32][64]             : 8192
#define WS_PART   835584       // fp32 [32*64][512]         : 4194304

#define STRIDE_ 520            // stash row stride in shorts (1040 B, 16B-aligned)

static __device__ __forceinline__ short f2bf(float f) {
  union { float f; uint32_t u; } v; v.f = f;
  uint32_t r = (v.u + 0x7FFFu + ((v.u >> 16) & 1u)) >> 16;
  return (short)(uint16_t)r;
}
static __device__ __forceinline__ float bf2f(uint32_t lo16) {
  union { uint32_t u; float f; } v; v.u = lo16 << 16; return v.f;
}
// packed RNE f32x2 -> bf16x2 (lo <- a, hi <- b); same rounding as f2bf
static __device__ __forceinline__ uint32_t cvt_pk_bf16(float a, float b) {
  uint32_t r;
  asm("v_cvt_pk_bf16_f32 %0, %1, %2" : "=v"(r) : "v"(a), "v"(b));
  return r;
}

// LDS-only barrier: drain lgkm (ds ops) but leave global loads in flight.
static __device__ __forceinline__ void lds_barrier() {
  asm volatile("s_waitcnt lgkmcnt(0)" ::: "memory");
  __builtin_amdgcn_s_barrier();
  asm volatile("" ::: "memory");
}

// ---------------- kernel 0: prep ------------------------------------------------
__global__ __launch_bounds__(256) void prep_kernel(
    const float* __restrict__ dh, const float* __restrict__ W_enc,
    const float* __restrict__ b_enc, const float* __restrict__ W_dec,
    const float* __restrict__ b_dec, unsigned short* __restrict__ WT,
    float* __restrict__ bias) {
  __shared__ float dh_s[512];
  __shared__ unsigned short tile[64 * 66];
  const int tid = threadIdx.x;
  if (blockIdx.x < 32) {
    const int b = blockIdx.x;
    dh_s[tid]       = dh[(size_t)b * H_ + tid];
    dh_s[tid + 256] = dh[(size_t)b * H_ + tid + 256];
    __syncthreads();
    float s[4] = {0.f, 0.f, 0.f, 0.f};
    for (int k = 0; k < H_; k += 32) {
      #pragma unroll
      for (int j = 0; j < 32; ++j)
        s[j & 3] = fmaf(dh_s[k + j], W_dec[(size_t)(k + j) * A_ + tid], s[j & 3]);
    }
    bias[b * A_ + tid] = s[0] + s[1] + s[2] + s[3] + b_enc[tid] + b_dec[tid];
  } else {
    const int t = blockIdx.x - 32;          // 0..31
    const int kt = t >> 2, nt2 = t & 3;     // k-tile (8), n-tile (4)
    #pragma unroll
    for (int i = 0; i < 16; ++i) {
      int idx = tid + i * 256;
      int kk = idx >> 6, nn = idx & 63;
      tile[kk * 66 + nn] =
          (unsigned short)f2bf(W_enc[(size_t)(kt * 64 + kk) * A_ + nt2 * 64 + nn]);
    }
    __syncthreads();
    #pragma unroll
    for (int i = 0; i < 16; ++i) {
      int idx = tid + i * 256;
      int nn = idx >> 6, kk = idx & 63;
      WT[(size_t)(nt2 * 64 + nn) * H_ + kt * 64 + kk] = tile[kk * 66 + nn];
    }
  }
}

// ---------------- kernel 1: fused (persistent) -----------------------------------
// grid 512 = 2 blocks/CU; each block processes 4 chunks (g, g+512, g+1024, g+1536).
// 4 waves; wave w owns col-tiles nt_g = w*4..w*4+3, all 4 m-tiles (rows 0..63).
__global__ __launch_bounds__(256, 2) void fused_kernel(
    const float* __restrict__ enc, const unsigned short* __restrict__ WT,
    const float* __restrict__ bias, const float* __restrict__ We,
    float* __restrict__ scores, float* __restrict__ wsm,
    float* __restrict__ wsl, float* __restrict__ part) {
  __shared__ __align__(16) unsigned short stash[64 * STRIDE_];  // 66560 B
  __shared__ float s_ps[4][64];                                  // per-wave row partials
  __shared__ float s_e[64];

  const int tid = threadIdx.x, w = tid >> 6, lane = tid & 63;
  const int lm = lane & 15, lq = lane >> 4;

  // ---- A staging addressing: thread t stages row tid>>2, k-span (tid&3)*8..+8
  const int arow = tid >> 2, akoff = (tid & 3) * 8;
  unsigned short* swp = &stash[arow * STRIDE_ + akoff];

  // ---- B reg-ring addressing: lane's frag for nt_g = w*4+j:
  //      WT[(nt_g*16+lm)*512 + kstep*32 + lq*8]
  const unsigned short* bptr = WT + (size_t)((w * 4) * 16 + lm) * H_ + lq * 8;

  short8 Bring[3][4];
  float4 Aring[3][2];   // ring slot s holds A(k) for k = s (mod 3)
  float4 a0a, a0b;      // A(0) of the upcoming chunk

  // ---- first-chunk prologue loads ----
  int g = blockIdx.x;                       // global chunk id (0..2047 over 4 iters)
  const float* aptr = enc + (size_t)(g * 64 + arow) * H_ + akoff;
  a0a = *(const float4*)aptr;
  a0b = *(const float4*)(aptr + 4);
  Aring[1][0] = *(const float4*)(aptr + 1 * 32);
  Aring[1][1] = *(const float4*)(aptr + 1 * 32 + 4);
  Aring[2][0] = *(const float4*)(aptr + 2 * 32);
  Aring[2][1] = *(const float4*)(aptr + 2 * 32 + 4);
  #pragma unroll
  for (int j = 0; j < 4; ++j) {
    Bring[0][j] = *(const short8*)(bptr + (size_t)j * 16 * H_);        // B(0)
    Bring[1][j] = *(const short8*)(bptr + (size_t)j * 16 * H_ + 32);   // B(1)
  }

  for (int it = 0; ; ++it) {
    const int b = g >> 6, chunk = g & 63;
    const int srow0 = g * 64;

    // ---- stash[0] from the prologue/prefetched A(0) ----
    {
      u32x4 sv;
      sv.x = cvt_pk_bf16(a0a.x, a0a.y); sv.y = cvt_pk_bf16(a0a.z, a0a.w);
      sv.z = cvt_pk_bf16(a0b.x, a0b.y); sv.w = cvt_pk_bf16(a0b.z, a0b.w);
      *(u32x4*)swp = sv;
    }
    lds_barrier();                          // stash[0] visible; loads in flight

    f32x4 acc[4][4];
    #pragma unroll
    for (int mt = 0; mt < 4; ++mt)
      #pragma unroll
      for (int nt = 0; nt < 4; ++nt)
        acc[mt][nt] = (f32x4){0.f, 0.f, 0.f, 0.f};

    #pragma unroll
    for (int k = 0; k < 16; ++k) {
      // prefetch A(k+3) into the ring slot freed at step k-1
      if (k + 3 < 16) {
        Aring[(k + 3) % 3][0] = *(const float4*)(aptr + (k + 3) * 32);
        Aring[(k + 3) % 3][1] = *(const float4*)(aptr + (k + 3) * 32 + 4);
      }
      // prefetch B(k+2) into ring slot (k+2)%3
      if (k + 2 < 16) {
        #pragma unroll
        for (int j = 0; j < 4; ++j)
          Bring[(k + 2) % 3][j] = *(const short8*)(bptr + (size_t)j * 16 * H_ + (k + 2) * 32);
      }
      // A fragments from stash; MFMA
      #pragma unroll
      for (int mt = 0; mt < 4; ++mt) {
        short8 af = *(const short8*)&stash[(mt * 16 + lm) * STRIDE_ + k * 32 + lq * 8];
        #pragma unroll
        for (int j = 0; j < 4; ++j)
          acc[mt][j] = __builtin_amdgcn_mfma_f32_16x16x32_bf16(af, Bring[k % 3][j], acc[mt][j], 0, 0, 0);
      }
      // write stash[k+1] from ring slot (k+1)%3
      if (k < 15) {
        float4 ca = Aring[(k + 1) % 3][0];
        float4 cb = Aring[(k + 1) % 3][1];
        u32x4 sv;
        sv.x = cvt_pk_bf16(ca.x, ca.y); sv.y = cvt_pk_bf16(ca.z, ca.w);
        sv.z = cvt_pk_bf16(cb.x, cb.y); sv.w = cvt_pk_bf16(cb.z, cb.w);
        *(u32x4*)(swp + (k + 1) * 32) = sv;
        lds_barrier();                      // stash[k+1] visible; prefetches in flight
      }
    }

    // ---- issue NEXT chunk's prologue loads; epilogue compute hides latency ----
    if (it < 3) {
      const int gn = g + 512;
      aptr = enc + (size_t)(gn * 64 + arow) * H_ + akoff;
      a0a = *(const float4*)aptr;
      a0b = *(const float4*)(aptr + 4);
      Aring[1][0] = *(const float4*)(aptr + 1 * 32);
      Aring[1][1] = *(const float4*)(aptr + 1 * 32 + 4);
      Aring[2][0] = *(const float4*)(aptr + 2 * 32);
      Aring[2][1] = *(const float4*)(aptr + 2 * 32 + 4);
      #pragma unroll
      for (int j = 0; j < 4; ++j) {
        Bring[0][j] = *(const short8*)(bptr + (size_t)j * 16 * H_);        // B(0)
        Bring[1][j] = *(const short8*)(bptr + (size_t)j * 16 * H_ + 32);   // B(1)
      }
    }

    // ---- epilogue: per-wave partial score over its 64 cols ----
    // C/D: col = (w*4+j)*16 + lm, row(in mt) = lq*4 + r
    float psum[4][4] = {{0,0,0,0},{0,0,0,0},{0,0,0,0},{0,0,0,0}};
    #pragma unroll
    for (int j = 0; j < 4; ++j) {
      const int col = (w * 4 + j) * 16 + lm;
      const float dp = bias[b * A_ + col];
      const float wv = We[col];
      #pragma unroll
      for (int mt = 0; mt < 4; ++mt)
        #pragma unroll
        for (int r = 0; r < 4; ++r) {
          float x = acc[mt][j][r] + dp;
          float e = __expf(2.0f * x);
          float t = 1.0f - 2.0f * __builtin_amdgcn_rcpf(e + 1.0f);
          psum[mt][r] = fmaf(t, wv, psum[mt][r]);
        }
    }
    #pragma unroll
    for (int o = 1; o < 16; o <<= 1)
      #pragma unroll
      for (int mt = 0; mt < 4; ++mt)
        #pragma unroll
        for (int r = 0; r < 4; ++r)
          psum[mt][r] += __shfl_xor(psum[mt][r], o, 64);
    if (lm == 0) {
      #pragma unroll
      for (int mt = 0; mt < 4; ++mt)
        #pragma unroll
        for (int r = 0; r < 4; ++r)
          s_ps[w][mt * 16 + lq * 4 + r] = psum[mt][r];
    }
    lds_barrier();

    // ---- cross-wave sum, chunk softmax (wave 0); store e = exp(sc - m) ----
    if (tid < 64) {
      const float sc = s_ps[0][tid] + s_ps[1][tid] + s_ps[2][tid] + s_ps[3][tid];
      float m = sc;
      #pragma unroll
      for (int o = 1; o < 64; o <<= 1) m = fmaxf(m, __shfl_xor(m, o, 64));
      const float e = __expf(sc - m);
      float l = e;
      #pragma unroll
      for (int o = 1; o < 64; o <<= 1) l += __shfl_xor(l, o, 64);
      s_e[tid] = e;
      scores[srow0 + tid] = e;             // store exp value, not raw score
      if (tid == 0) {
        wsm[b * CHUNKS_ + chunk] = m;
        wsl[b * CHUNKS_ + chunk] = l;
      }
    }
    lds_barrier();

    // ---- phase 2: context partial from LDS stash (no global enc re-read) ----
    float cx0 = 0.f, cx1 = 0.f;
    #pragma unroll 8
    for (int row = 0; row < 64; ++row) {
      uint32_t pv = *(const uint32_t*)&stash[row * STRIDE_ + (tid << 1)];
      float wr = s_e[row];
      cx0 = fmaf(wr, bf2f(pv & 0xffffu), cx0);
      cx1 = fmaf(wr, bf2f(pv >> 16), cx1);
    }
    float2 o2; o2.x = cx0; o2.y = cx1;
    *(float2*)&part[(size_t)(b * CHUNKS_ + chunk) * H_ + (tid << 1)] = o2;

    if (it == 3) break;
    g += 512;
    lds_barrier();                          // phase-2 stash reads done before next stash[0]
  }
}

// ---------------- kernel 2: finalize --------------------------------------------
// grid 256 = 32 b x 8 slices. Each block redoes the tiny 64-chunk M/L reduce,
// then handles 64 ctx cols and 512 attn elems.
__global__ __launch_bounds__(256) void finalize_kernel(
    const float* __restrict__ scores_e, const float* __restrict__ wsm,
    const float* __restrict__ wsl, const float* __restrict__ part,
    float* __restrict__ ctx, float* __restrict__ attn) {
  __shared__ float wgt[CHUNKS_];
  __shared__ float s_inv;
  __shared__ float csum[4][64];
  const int b = blockIdx.x >> 3, j = blockIdx.x & 7;
  const int tid = threadIdx.x;
  if (tid < 64) {
    float mc = wsm[b * CHUNKS_ + tid];
    float lc = wsl[b * CHUNKS_ + tid];
    float M = mc;
    #pragma unroll
    for (int o = 1; o < 64; o <<= 1) M = fmaxf(M, __shfl_xor(M, o, 64));
    float wv = __expf(mc - M);
    float Lp = wv * lc;
    #pragma unroll
    for (int o = 1; o < 64; o <<= 1) Lp += __shfl_xor(Lp, o, 64);
    wgt[tid] = wv;
    if (tid == 0) s_inv = 1.0f / Lp;
  }
  __syncthreads();
  const float invL = s_inv;

  // ctx slice: h = j*64 + (tid&63); chunk-quarter g = tid>>6 sums 16 chunks
  {
    const int h = j * 64 + (tid & 63), gq = tid >> 6;
    float s = 0.f;
    #pragma unroll 4
    for (int c = gq * 16; c < gq * 16 + 16; ++c)
      s = fmaf(wgt[c], part[(size_t)(b * CHUNKS_ + c) * H_ + h], s);
    csum[gq][tid & 63] = s;
  }
  __syncthreads();
  if (tid < 64) {
    float s = csum[0][tid] + csum[1][tid] + csum[2][tid] + csum[3][tid];
    ctx[(size_t)b * H_ + j * 64 + tid] = s * invL;
  }

  // attn slice: 512 elems, reuse stored e = exp(sc - m_chunk)
  #pragma unroll
  for (int i = 0; i < 2; ++i) {
    const int s_ = j * 512 + tid + i * 256;
    attn[(size_t)b * S_ + s_] = scores_e[(size_t)b * S_ + s_] * wgt[s_ >> 6] * invL;
  }
}

extern "C" void kernel_launch(void* const* d_in, const int* in_sizes, int n_in,
                              void* d_out, int out_size, void* d_ws, size_t ws_size,
                              hipStream_t stream) {
  const float* enc   = (const float*)d_in[0];
  const float* dh    = (const float*)d_in[1];
  const float* W_enc = (const float*)d_in[2];
  const float* b_enc = (const float*)d_in[3];
  const float* W_dec = (const float*)d_in[4];
  const float* b_dec = (const float*)d_in[5];
  const float* W_e   = (const float*)d_in[6];
  // b_e (d_in[7]) dropped: softmax is shift-invariant, scores not an output.

  char* ws = (char*)d_ws;
  unsigned short* WT = (unsigned short*)(ws + WS_WT);
  float* bias   = (float*)(ws + WS_BIAS);
  float* scores = (float*)(ws + WS_SCORES);
  float* wsm    = (float*)(ws + WS_M);
  float* wsl    = (float*)(ws + WS_L);
  float* part   = (float*)(ws + WS_PART);

  float* ctx  = (float*)d_out;            // [32][512]
  float* attn = (float*)d_out + B_ * H_;  // [32][4096]

  prep_kernel<<<dim3(64), dim3(256), 0, stream>>>(dh, W_enc, b_enc, W_dec, b_dec, WT, bias);
  fused_kernel<<<dim3(512), dim3(256), 0, stream>>>(enc, WT, bias, W_e, scores, wsm, wsl, part);
  finalize_kernel<<<dim3(256), dim3(256), 0, stream>>>(scores, wsm, wsl, part, ctx, attn);
}

// Round 3
// 411.272 us; speedup vs baseline: 1.0478x; 1.0478x over previous
//
#include <hip/hip_runtime.h>
#include <hip/hip_bf16.h>
#include <stdint.h>

// AdditiveAttention: B=32, S=4096, H=512, A=256
// d_out = [context: 32*512][attn: 32*4096]  (fp32)
//
// R7: revert R6's persistence + asm cvt_pk (regression). Back to grid-2048
// R5 structure, with the k-loop barrier count halved: stash write-ahead-2
// (write region k+2 at step k; stash holds all 16 disjoint k-regions so no
// aliasing) -> lds_barrier only after odd steps (8 barriers, was 16).
// A register ring deepened to 4 slots (load lead-4, 2-step consume slack).

typedef __attribute__((ext_vector_type(4))) float f32x4;
typedef __attribute__((ext_vector_type(8))) short short8;

#define B_  32
#define S_  4096
#define H_  512
#define A_  256
#define CHUNKS_ 64   // 4096 / 64 rows per block

// ---- workspace layout (bytes) ----
#define WS_WT     0            // bf16 W_enc^T [256][512]   : 262144
#define WS_BIAS   262144       // fp32 [32][256]            : 32768
#define WS_SCORES 294912       // fp32 [32][4096] (exp vals): 524288
#define WS_M      819200       // fp32 [32][64]             : 8192
#define WS_L      827392       // fp32 [32][64]             : 8192
#define WS_PART   835584       // fp32 [32*64][512]         : 4194304

#define STRIDE_ 520            // stash row stride in shorts (1040 B, 16B-aligned)

static __device__ __forceinline__ short f2bf(float f) {
  union { float f; uint32_t u; } v; v.f = f;
  uint32_t r = (v.u + 0x7FFFu + ((v.u >> 16) & 1u)) >> 16;
  return (short)(uint16_t)r;
}
static __device__ __forceinline__ float bf2f(uint32_t lo16) {
  union { uint32_t u; float f; } v; v.u = lo16 << 16; return v.f;
}

// LDS-only barrier: drain lgkm (ds ops) but leave global loads in flight.
static __device__ __forceinline__ void lds_barrier() {
  asm volatile("s_waitcnt lgkmcnt(0)" ::: "memory");
  __builtin_amdgcn_s_barrier();
  asm volatile("" ::: "memory");
}

// ---------------- kernel 0: prep ------------------------------------------------
__global__ __launch_bounds__(256) void prep_kernel(
    const float* __restrict__ dh, const float* __restrict__ W_enc,
    const float* __restrict__ b_enc, const float* __restrict__ W_dec,
    const float* __restrict__ b_dec, unsigned short* __restrict__ WT,
    float* __restrict__ bias) {
  __shared__ float dh_s[512];
  __shared__ unsigned short tile[64 * 66];
  const int tid = threadIdx.x;
  if (blockIdx.x < 32) {
    const int b = blockIdx.x;
    dh_s[tid]       = dh[(size_t)b * H_ + tid];
    dh_s[tid + 256] = dh[(size_t)b * H_ + tid + 256];
    __syncthreads();
    float s[4] = {0.f, 0.f, 0.f, 0.f};
    for (int k = 0; k < H_; k += 32) {
      #pragma unroll
      for (int j = 0; j < 32; ++j)
        s[j & 3] = fmaf(dh_s[k + j], W_dec[(size_t)(k + j) * A_ + tid], s[j & 3]);
    }
    bias[b * A_ + tid] = s[0] + s[1] + s[2] + s[3] + b_enc[tid] + b_dec[tid];
  } else {
    const int t = blockIdx.x - 32;          // 0..31
    const int kt = t >> 2, nt2 = t & 3;     // k-tile (8), n-tile (4)
    #pragma unroll
    for (int i = 0; i < 16; ++i) {
      int idx = tid + i * 256;
      int kk = idx >> 6, nn = idx & 63;
      tile[kk * 66 + nn] =
          (unsigned short)f2bf(W_enc[(size_t)(kt * 64 + kk) * A_ + nt2 * 64 + nn]);
    }
    __syncthreads();
    #pragma unroll
    for (int i = 0; i < 16; ++i) {
      int idx = tid + i * 256;
      int nn = idx >> 6, kk = idx & 63;
      WT[(size_t)(nt2 * 64 + nn) * H_ + kt * 64 + kk] = tile[kk * 66 + nn];
    }
  }
}

// ---------------- kernel 1: fused -----------------------------------------------
// grid 2048 = 32 b x 64 chunks of 64 rows. 4 waves; wave w owns col-tiles
// nt_g = w*4..w*4+3 (cols w*64..+63), all 4 m-tiles (rows 0..63).
__global__ __launch_bounds__(256, 2) void fused_kernel(
    const float* __restrict__ enc, const unsigned short* __restrict__ WT,
    const float* __restrict__ bias, const float* __restrict__ We,
    float* __restrict__ scores, float* __restrict__ wsm,
    float* __restrict__ wsl, float* __restrict__ part) {
  __shared__ __align__(16) unsigned short stash[64 * STRIDE_];  // 66560 B
  __shared__ float s_ps[4][64];                                  // per-wave row partials
  __shared__ float s_e[64];

  const int tid = threadIdx.x, w = tid >> 6, lane = tid & 63;
  const int lm = lane & 15, lq = lane >> 4;
  const int b = blockIdx.x >> 6;
  const int chunk = blockIdx.x & 63;
  const int srow0 = blockIdx.x * 64;        // flat (b*S + s) row base

  f32x4 acc[4][4];
  #pragma unroll
  for (int mt = 0; mt < 4; ++mt)
    #pragma unroll
    for (int nt = 0; nt < 4; ++nt)
      acc[mt][nt] = (f32x4){0.f, 0.f, 0.f, 0.f};

  // ---- A staging addressing: thread t stages row tid>>2, k-span (tid&3)*8..+8
  const int arow = tid >> 2, akoff = (tid & 3) * 8;
  const float* aptr = enc + (size_t)(srow0 + arow) * H_ + akoff;
  unsigned short* swp = &stash[arow * STRIDE_ + akoff];

  // ---- B reg-ring addressing: lane's frag for nt_g = w*4+j:
  //      WT[(nt_g*16+lm)*512 + kstep*32 + lq*8]
  const unsigned short* bptr = WT + (size_t)((w * 4) * 16 + lm) * H_ + lq * 8;

  short8 Bring[3][4];
  float4 Ar[4][2];   // ring slot s holds A(k), k = s (mod 4); load lead-4

  // ---- prologue: A(0),A(1) staged direct; ring slots 2,3 <- A(2),A(3);
  //      B(0),B(1) into Bring ----
  float4 a0a = *(const float4*)aptr;
  float4 a0b = *(const float4*)(aptr + 4);
  float4 a1a = *(const float4*)(aptr + 32);
  float4 a1b = *(const float4*)(aptr + 36);
  Ar[2][0] = *(const float4*)(aptr + 2 * 32);
  Ar[2][1] = *(const float4*)(aptr + 2 * 32 + 4);
  Ar[3][0] = *(const float4*)(aptr + 3 * 32);
  Ar[3][1] = *(const float4*)(aptr + 3 * 32 + 4);
  #pragma unroll
  for (int j = 0; j < 4; ++j) {
    Bring[0][j] = *(const short8*)(bptr + (size_t)j * 16 * H_);        // B(0)
    Bring[1][j] = *(const short8*)(bptr + (size_t)j * 16 * H_ + 32);   // B(1)
  }
  {
    short8 sv;
    sv[0] = f2bf(a0a.x); sv[1] = f2bf(a0a.y); sv[2] = f2bf(a0a.z); sv[3] = f2bf(a0a.w);
    sv[4] = f2bf(a0b.x); sv[5] = f2bf(a0b.y); sv[6] = f2bf(a0b.z); sv[7] = f2bf(a0b.w);
    *(short8*)swp = sv;                     // stash region 0
    sv[0] = f2bf(a1a.x); sv[1] = f2bf(a1a.y); sv[2] = f2bf(a1a.z); sv[3] = f2bf(a1a.w);
    sv[4] = f2bf(a1b.x); sv[5] = f2bf(a1b.y); sv[6] = f2bf(a1b.z); sv[7] = f2bf(a1b.w);
    *(short8*)(swp + 32) = sv;              // stash region 1
  }
  lds_barrier();                            // regions 0,1 visible; loads in flight

  #pragma unroll
  for (int k = 0; k < 16; ++k) {
    // prefetch A(k+4) into ring slot k%4 (freed: A(k) consumed at step k-2)
    if (k < 12) {
      Ar[k & 3][0] = *(const float4*)(aptr + (k + 4) * 32);
      Ar[k & 3][1] = *(const float4*)(aptr + (k + 4) * 32 + 4);
    }
    // prefetch B(k+2) into ring slot (k+2)%3
    if (k < 14) {
      #pragma unroll
      for (int j = 0; j < 4; ++j)
        Bring[(k + 2) % 3][j] = *(const short8*)(bptr + (size_t)j * 16 * H_ + (k + 2) * 32);
    }
    // A fragments from stash region k; MFMA
    #pragma unroll
    for (int mt = 0; mt < 4; ++mt) {
      short8 af = *(const short8*)&stash[(mt * 16 + lm) * STRIDE_ + k * 32 + lq * 8];
      #pragma unroll
      for (int j = 0; j < 4; ++j)
        acc[mt][j] = __builtin_amdgcn_mfma_f32_16x16x32_bf16(af, Bring[k % 3][j], acc[mt][j], 0, 0, 0);
    }
    // write stash region k+2 from ring slot (k+2)%4 (loaded at step k-2)
    if (k < 14) {
      float4 ca = Ar[(k + 2) & 3][0];
      float4 cb = Ar[(k + 2) & 3][1];
      short8 sv;
      sv[0] = f2bf(ca.x); sv[1] = f2bf(ca.y); sv[2] = f2bf(ca.z); sv[3] = f2bf(ca.w);
      sv[4] = f2bf(cb.x); sv[5] = f2bf(cb.y); sv[6] = f2bf(cb.z); sv[7] = f2bf(cb.w);
      *(short8*)(swp + (k + 2) * 32) = sv;
    }
    // barrier after odd steps only: write(region r)@step r-2 and read@step r
    // always have one barrier in between (same-parity write/read).
    if (k & 1) lds_barrier();
  }

  // ---- epilogue: per-wave partial score over its 64 cols ----
  // C/D: col = (w*4+j)*16 + lm, row(in mt) = lq*4 + r
  float psum[4][4] = {{0,0,0,0},{0,0,0,0},{0,0,0,0},{0,0,0,0}};
  #pragma unroll
  for (int j = 0; j < 4; ++j) {
    const int col = (w * 4 + j) * 16 + lm;
    const float dp = bias[b * A_ + col];
    const float wv = We[col];
    #pragma unroll
    for (int mt = 0; mt < 4; ++mt)
      #pragma unroll
      for (int r = 0; r < 4; ++r) {
        float x = acc[mt][j][r] + dp;
        float e = __expf(2.0f * x);
        float t = 1.0f - 2.0f * __builtin_amdgcn_rcpf(e + 1.0f);
        psum[mt][r] = fmaf(t, wv, psum[mt][r]);
      }
  }
  #pragma unroll
  for (int o = 1; o < 16; o <<= 1)
    #pragma unroll
    for (int mt = 0; mt < 4; ++mt)
      #pragma unroll
      for (int r = 0; r < 4; ++r)
        psum[mt][r] += __shfl_xor(psum[mt][r], o, 64);
  if (lm == 0) {
    #pragma unroll
    for (int mt = 0; mt < 4; ++mt)
      #pragma unroll
      for (int r = 0; r < 4; ++r)
        s_ps[w][mt * 16 + lq * 4 + r] = psum[mt][r];
  }
  lds_barrier();

  // ---- cross-wave sum, chunk softmax (wave 0); store e = exp(sc - m) ----
  if (tid < 64) {
    const float sc = s_ps[0][tid] + s_ps[1][tid] + s_ps[2][tid] + s_ps[3][tid];
    float m = sc;
    #pragma unroll
    for (int o = 1; o < 64; o <<= 1) m = fmaxf(m, __shfl_xor(m, o, 64));
    const float e = __expf(sc - m);
    float l = e;
    #pragma unroll
    for (int o = 1; o < 64; o <<= 1) l += __shfl_xor(l, o, 64);
    s_e[tid] = e;
    scores[srow0 + tid] = e;               // store exp value, not raw score
    if (tid == 0) {
      wsm[b * CHUNKS_ + chunk] = m;
      wsl[b * CHUNKS_ + chunk] = l;
    }
  }
  lds_barrier();

  // ---- phase 2: context partial from LDS stash (no global enc re-read) ----
  float cx0 = 0.f, cx1 = 0.f;
  #pragma unroll 8
  for (int row = 0; row < 64; ++row) {
    uint32_t pv = *(const uint32_t*)&stash[row * STRIDE_ + (tid << 1)];
    float wr = s_e[row];
    cx0 = fmaf(wr, bf2f(pv & 0xffffu), cx0);
    cx1 = fmaf(wr, bf2f(pv >> 16), cx1);
  }
  float2 o2; o2.x = cx0; o2.y = cx1;
  *(float2*)&part[(size_t)(b * CHUNKS_ + chunk) * H_ + (tid << 1)] = o2;
}

// ---------------- kernel 2: finalize --------------------------------------------
// grid 256 = 32 b x 8 slices. Each block redoes the tiny 64-chunk M/L reduce,
// then handles 64 ctx cols and 512 attn elems.
__global__ __launch_bounds__(256) void finalize_kernel(
    const float* __restrict__ scores_e, const float* __restrict__ wsm,
    const float* __restrict__ wsl, const float* __restrict__ part,
    float* __restrict__ ctx, float* __restrict__ attn) {
  __shared__ float wgt[CHUNKS_];
  __shared__ float s_inv;
  __shared__ float csum[4][64];
  const int b = blockIdx.x >> 3, j = blockIdx.x & 7;
  const int tid = threadIdx.x;
  if (tid < 64) {
    float mc = wsm[b * CHUNKS_ + tid];
    float lc = wsl[b * CHUNKS_ + tid];
    float M = mc;
    #pragma unroll
    for (int o = 1; o < 64; o <<= 1) M = fmaxf(M, __shfl_xor(M, o, 64));
    float wv = __expf(mc - M);
    float Lp = wv * lc;
    #pragma unroll
    for (int o = 1; o < 64; o <<= 1) Lp += __shfl_xor(Lp, o, 64);
    wgt[tid] = wv;
    if (tid == 0) s_inv = 1.0f / Lp;
  }
  __syncthreads();
  const float invL = s_inv;

  // ctx slice: h = j*64 + (tid&63); chunk-quarter g = tid>>6 sums 16 chunks
  {
    const int h = j * 64 + (tid & 63), gq = tid >> 6;
    float s = 0.f;
    #pragma unroll 4
    for (int c = gq * 16; c < gq * 16 + 16; ++c)
      s = fmaf(wgt[c], part[(size_t)(b * CHUNKS_ + c) * H_ + h], s);
    csum[gq][tid & 63] = s;
  }
  __syncthreads();
  if (tid < 64) {
    float s = csum[0][tid] + csum[1][tid] + csum[2][tid] + csum[3][tid];
    ctx[(size_t)b * H_ + j * 64 + tid] = s * invL;
  }

  // attn slice: 512 elems, reuse stored e = exp(sc - m_chunk)
  #pragma unroll
  for (int i = 0; i < 2; ++i) {
    const int s_ = j * 512 + tid + i * 256;
    attn[(size_t)b * S_ + s_] = scores_e[(size_t)b * S_ + s_] * wgt[s_ >> 6] * invL;
  }
}

extern "C" void kernel_launch(void* const* d_in, const int* in_sizes, int n_in,
                              void* d_out, int out_size, void* d_ws, size_t ws_size,
                              hipStream_t stream) {
  const float* enc   = (const float*)d_in[0];
  const float* dh    = (const float*)d_in[1];
  const float* W_enc = (const float*)d_in[2];
  const float* b_enc = (const float*)d_in[3];
  const float* W_dec = (const float*)d_in[4];
  const float* b_dec = (const float*)d_in[5];
  const float* W_e   = (const float*)d_in[6];
  // b_e (d_in[7]) dropped: softmax is shift-invariant, scores not an output.

  char* ws = (char*)d_ws;
  unsigned short* WT = (unsigned short*)(ws + WS_WT);
  float* bias   = (float*)(ws + WS_BIAS);
  float* scores = (float*)(ws + WS_SCORES);
  float* wsm    = (float*)(ws + WS_M);
  float* wsl    = (float*)(ws + WS_L);
  float* part   = (float*)(ws + WS_PART);

  float* ctx  = (float*)d_out;            // [32][512]
  float* attn = (float*)d_out + B_ * H_;  // [32][4096]

  prep_kernel<<<dim3(64), dim3(256), 0, stream>>>(dh, W_enc, b_enc, W_dec, b_dec, WT, bias);
  fused_kernel<<<dim3(2048), dim3(256), 0, stream>>>(enc, WT, bias, W_e, scores, wsm, wsl, part);
  finalize_kernel<<<dim3(256), dim3(256), 0, stream>>>(scores, wsm, wsl, part, ctx, attn);
}

// Round 4
// 404.060 us; speedup vs baseline: 1.0665x; 1.0178x over previous
//
#include <hip/hip_runtime.h>
#include <hip/hip_bf16.h>
#include <stdint.h>

// AdditiveAttention: B=32, S=4096, H=512, A=256
// d_out = [context: 32*512][attn: 32*4096]  (fp32)
//
// R8: A register ring deepened 4 -> 6 slots. At step k: issue A(k+6),
// stash-write A(k+2) (issued at k-4) -> 4 steps (~640-900 cyc) of HBM-latency
// slack, vs 2 steps (~350 cyc) before. Everything else identical to R7
// (write-ahead-2 stash, barrier after odd steps, grid 2048, 2 blocks/CU).

typedef __attribute__((ext_vector_type(4))) float f32x4;
typedef __attribute__((ext_vector_type(8))) short short8;

#define B_  32
#define S_  4096
#define H_  512
#define A_  256
#define CHUNKS_ 64   // 4096 / 64 rows per block

// ---- workspace layout (bytes) ----
#define WS_WT     0            // bf16 W_enc^T [256][512]   : 262144
#define WS_BIAS   262144       // fp32 [32][256]            : 32768
#define WS_SCORES 294912       // fp32 [32][4096] (exp vals): 524288
#define WS_M      819200       // fp32 [32][64]             : 8192
#define WS_L      827392       // fp32 [32][64]             : 8192
#define WS_PART   835584       // fp32 [32*64][512]         : 4194304

#define STRIDE_ 520            // stash row stride in shorts (1040 B, 16B-aligned)

static __device__ __forceinline__ short f2bf(float f) {
  union { float f; uint32_t u; } v; v.f = f;
  uint32_t r = (v.u + 0x7FFFu + ((v.u >> 16) & 1u)) >> 16;
  return (short)(uint16_t)r;
}
static __device__ __forceinline__ float bf2f(uint32_t lo16) {
  union { uint32_t u; float f; } v; v.u = lo16 << 16; return v.f;
}

// LDS-only barrier: drain lgkm (ds ops) but leave global loads in flight.
static __device__ __forceinline__ void lds_barrier() {
  asm volatile("s_waitcnt lgkmcnt(0)" ::: "memory");
  __builtin_amdgcn_s_barrier();
  asm volatile("" ::: "memory");
}

// ---------------- kernel 0: prep ------------------------------------------------
__global__ __launch_bounds__(256) void prep_kernel(
    const float* __restrict__ dh, const float* __restrict__ W_enc,
    const float* __restrict__ b_enc, const float* __restrict__ W_dec,
    const float* __restrict__ b_dec, unsigned short* __restrict__ WT,
    float* __restrict__ bias) {
  __shared__ float dh_s[512];
  __shared__ unsigned short tile[64 * 66];
  const int tid = threadIdx.x;
  if (blockIdx.x < 32) {
    const int b = blockIdx.x;
    dh_s[tid]       = dh[(size_t)b * H_ + tid];
    dh_s[tid + 256] = dh[(size_t)b * H_ + tid + 256];
    __syncthreads();
    float s[4] = {0.f, 0.f, 0.f, 0.f};
    for (int k = 0; k < H_; k += 32) {
      #pragma unroll
      for (int j = 0; j < 32; ++j)
        s[j & 3] = fmaf(dh_s[k + j], W_dec[(size_t)(k + j) * A_ + tid], s[j & 3]);
    }
    bias[b * A_ + tid] = s[0] + s[1] + s[2] + s[3] + b_enc[tid] + b_dec[tid];
  } else {
    const int t = blockIdx.x - 32;          // 0..31
    const int kt = t >> 2, nt2 = t & 3;     // k-tile (8), n-tile (4)
    #pragma unroll
    for (int i = 0; i < 16; ++i) {
      int idx = tid + i * 256;
      int kk = idx >> 6, nn = idx & 63;
      tile[kk * 66 + nn] =
          (unsigned short)f2bf(W_enc[(size_t)(kt * 64 + kk) * A_ + nt2 * 64 + nn]);
    }
    __syncthreads();
    #pragma unroll
    for (int i = 0; i < 16; ++i) {
      int idx = tid + i * 256;
      int nn = idx >> 6, kk = idx & 63;
      WT[(size_t)(nt2 * 64 + nn) * H_ + kt * 64 + kk] = tile[kk * 66 + nn];
    }
  }
}

// ---------------- kernel 1: fused -----------------------------------------------
// grid 2048 = 32 b x 64 chunks of 64 rows. 4 waves; wave w owns col-tiles
// nt_g = w*4..w*4+3 (cols w*64..+63), all 4 m-tiles (rows 0..63).
__global__ __launch_bounds__(256, 2) void fused_kernel(
    const float* __restrict__ enc, const unsigned short* __restrict__ WT,
    const float* __restrict__ bias, const float* __restrict__ We,
    float* __restrict__ scores, float* __restrict__ wsm,
    float* __restrict__ wsl, float* __restrict__ part) {
  __shared__ __align__(16) unsigned short stash[64 * STRIDE_];  // 66560 B
  __shared__ float s_ps[4][64];                                  // per-wave row partials
  __shared__ float s_e[64];

  const int tid = threadIdx.x, w = tid >> 6, lane = tid & 63;
  const int lm = lane & 15, lq = lane >> 4;
  const int b = blockIdx.x >> 6;
  const int chunk = blockIdx.x & 63;
  const int srow0 = blockIdx.x * 64;        // flat (b*S + s) row base

  f32x4 acc[4][4];
  #pragma unroll
  for (int mt = 0; mt < 4; ++mt)
    #pragma unroll
    for (int nt = 0; nt < 4; ++nt)
      acc[mt][nt] = (f32x4){0.f, 0.f, 0.f, 0.f};

  // ---- A staging addressing: thread t stages row tid>>2, k-span (tid&3)*8..+8
  const int arow = tid >> 2, akoff = (tid & 3) * 8;
  const float* aptr = enc + (size_t)(srow0 + arow) * H_ + akoff;
  unsigned short* swp = &stash[arow * STRIDE_ + akoff];

  // ---- B reg-ring addressing: lane's frag for nt_g = w*4+j:
  //      WT[(nt_g*16+lm)*512 + kstep*32 + lq*8]
  const unsigned short* bptr = WT + (size_t)((w * 4) * 16 + lm) * H_ + lq * 8;

  short8 Bring[3][4];
  float4 Ar[6][2];   // ring slot s holds A(k), k = s (mod 6); issue lead-6

  // ---- prologue: A(0),A(1) staged direct; ring slots 2..5 <- A(2)..A(5);
  //      B(0),B(1) into Bring ----
  float4 a0a = *(const float4*)aptr;
  float4 a0b = *(const float4*)(aptr + 4);
  float4 a1a = *(const float4*)(aptr + 32);
  float4 a1b = *(const float4*)(aptr + 36);
  #pragma unroll
  for (int p = 2; p < 6; ++p) {
    Ar[p][0] = *(const float4*)(aptr + p * 32);
    Ar[p][1] = *(const float4*)(aptr + p * 32 + 4);
  }
  #pragma unroll
  for (int j = 0; j < 4; ++j) {
    Bring[0][j] = *(const short8*)(bptr + (size_t)j * 16 * H_);        // B(0)
    Bring[1][j] = *(const short8*)(bptr + (size_t)j * 16 * H_ + 32);   // B(1)
  }
  {
    short8 sv;
    sv[0] = f2bf(a0a.x); sv[1] = f2bf(a0a.y); sv[2] = f2bf(a0a.z); sv[3] = f2bf(a0a.w);
    sv[4] = f2bf(a0b.x); sv[5] = f2bf(a0b.y); sv[6] = f2bf(a0b.z); sv[7] = f2bf(a0b.w);
    *(short8*)swp = sv;                     // stash region 0
    sv[0] = f2bf(a1a.x); sv[1] = f2bf(a1a.y); sv[2] = f2bf(a1a.z); sv[3] = f2bf(a1a.w);
    sv[4] = f2bf(a1b.x); sv[5] = f2bf(a1b.y); sv[6] = f2bf(a1b.z); sv[7] = f2bf(a1b.w);
    *(short8*)(swp + 32) = sv;              // stash region 1
  }
  lds_barrier();                            // regions 0,1 visible; loads in flight

  #pragma unroll
  for (int k = 0; k < 16; ++k) {
    // prefetch A(k+6) into ring slot k%6 (A(k) was consumed at step k-2)
    if (k < 10) {
      Ar[k % 6][0] = *(const float4*)(aptr + (k + 6) * 32);
      Ar[k % 6][1] = *(const float4*)(aptr + (k + 6) * 32 + 4);
    }
    // prefetch B(k+2) into ring slot (k+2)%3
    if (k < 14) {
      #pragma unroll
      for (int j = 0; j < 4; ++j)
        Bring[(k + 2) % 3][j] = *(const short8*)(bptr + (size_t)j * 16 * H_ + (k + 2) * 32);
    }
    // A fragments from stash region k; MFMA
    #pragma unroll
    for (int mt = 0; mt < 4; ++mt) {
      short8 af = *(const short8*)&stash[(mt * 16 + lm) * STRIDE_ + k * 32 + lq * 8];
      #pragma unroll
      for (int j = 0; j < 4; ++j)
        acc[mt][j] = __builtin_amdgcn_mfma_f32_16x16x32_bf16(af, Bring[k % 3][j], acc[mt][j], 0, 0, 0);
    }
    // write stash region k+2 from ring slot (k+2)%6 (issued at step k-4)
    if (k < 14) {
      float4 ca = Ar[(k + 2) % 6][0];
      float4 cb = Ar[(k + 2) % 6][1];
      short8 sv;
      sv[0] = f2bf(ca.x); sv[1] = f2bf(ca.y); sv[2] = f2bf(ca.z); sv[3] = f2bf(ca.w);
      sv[4] = f2bf(cb.x); sv[5] = f2bf(cb.y); sv[6] = f2bf(cb.z); sv[7] = f2bf(cb.w);
      *(short8*)(swp + (k + 2) * 32) = sv;
    }
    // barrier after odd steps only: write(region r)@step r-2 and read@step r
    // always have one barrier in between (same-parity write/read).
    if (k & 1) lds_barrier();
  }

  // ---- epilogue: per-wave partial score over its 64 cols ----
  // C/D: col = (w*4+j)*16 + lm, row(in mt) = lq*4 + r
  float psum[4][4] = {{0,0,0,0},{0,0,0,0},{0,0,0,0},{0,0,0,0}};
  #pragma unroll
  for (int j = 0; j < 4; ++j) {
    const int col = (w * 4 + j) * 16 + lm;
    const float dp = bias[b * A_ + col];
    const float wv = We[col];
    #pragma unroll
    for (int mt = 0; mt < 4; ++mt)
      #pragma unroll
      for (int r = 0; r < 4; ++r) {
        float x = acc[mt][j][r] + dp;
        float e = __expf(2.0f * x);
        float t = 1.0f - 2.0f * __builtin_amdgcn_rcpf(e + 1.0f);
        psum[mt][r] = fmaf(t, wv, psum[mt][r]);
      }
  }
  #pragma unroll
  for (int o = 1; o < 16; o <<= 1)
    #pragma unroll
    for (int mt = 0; mt < 4; ++mt)
      #pragma unroll
      for (int r = 0; r < 4; ++r)
        psum[mt][r] += __shfl_xor(psum[mt][r], o, 64);
  if (lm == 0) {
    #pragma unroll
    for (int mt = 0; mt < 4; ++mt)
      #pragma unroll
      for (int r = 0; r < 4; ++r)
        s_ps[w][mt * 16 + lq * 4 + r] = psum[mt][r];
  }
  lds_barrier();

  // ---- cross-wave sum, chunk softmax (wave 0); store e = exp(sc - m) ----
  if (tid < 64) {
    const float sc = s_ps[0][tid] + s_ps[1][tid] + s_ps[2][tid] + s_ps[3][tid];
    float m = sc;
    #pragma unroll
    for (int o = 1; o < 64; o <<= 1) m = fmaxf(m, __shfl_xor(m, o, 64));
    const float e = __expf(sc - m);
    float l = e;
    #pragma unroll
    for (int o = 1; o < 64; o <<= 1) l += __shfl_xor(l, o, 64);
    s_e[tid] = e;
    scores[srow0 + tid] = e;               // store exp value, not raw score
    if (tid == 0) {
      wsm[b * CHUNKS_ + chunk] = m;
      wsl[b * CHUNKS_ + chunk] = l;
    }
  }
  lds_barrier();

  // ---- phase 2: context partial from LDS stash (no global enc re-read) ----
  float cx0 = 0.f, cx1 = 0.f;
  #pragma unroll 8
  for (int row = 0; row < 64; ++row) {
    uint32_t pv = *(const uint32_t*)&stash[row * STRIDE_ + (tid << 1)];
    float wr = s_e[row];
    cx0 = fmaf(wr, bf2f(pv & 0xffffu), cx0);
    cx1 = fmaf(wr, bf2f(pv >> 16), cx1);
  }
  float2 o2; o2.x = cx0; o2.y = cx1;
  *(float2*)&part[(size_t)(b * CHUNKS_ + chunk) * H_ + (tid << 1)] = o2;
}

// ---------------- kernel 2: finalize --------------------------------------------
// grid 256 = 32 b x 8 slices. Each block redoes the tiny 64-chunk M/L reduce,
// then handles 64 ctx cols and 512 attn elems.
__global__ __launch_bounds__(256) void finalize_kernel(
    const float* __restrict__ scores_e, const float* __restrict__ wsm,
    const float* __restrict__ wsl, const float* __restrict__ part,
    float* __restrict__ ctx, float* __restrict__ attn) {
  __shared__ float wgt[CHUNKS_];
  __shared__ float s_inv;
  __shared__ float csum[4][64];
  const int b = blockIdx.x >> 3, j = blockIdx.x & 7;
  const int tid = threadIdx.x;
  if (tid < 64) {
    float mc = wsm[b * CHUNKS_ + tid];
    float lc = wsl[b * CHUNKS_ + tid];
    float M = mc;
    #pragma unroll
    for (int o = 1; o < 64; o <<= 1) M = fmaxf(M, __shfl_xor(M, o, 64));
    float wv = __expf(mc - M);
    float Lp = wv * lc;
    #pragma unroll
    for (int o = 1; o < 64; o <<= 1) Lp += __shfl_xor(Lp, o, 64);
    wgt[tid] = wv;
    if (tid == 0) s_inv = 1.0f / Lp;
  }
  __syncthreads();
  const float invL = s_inv;

  // ctx slice: h = j*64 + (tid&63); chunk-quarter g = tid>>6 sums 16 chunks
  {
    const int h = j * 64 + (tid & 63), gq = tid >> 6;
    float s = 0.f;
    #pragma unroll 4
    for (int c = gq * 16; c < gq * 16 + 16; ++c)
      s = fmaf(wgt[c], part[(size_t)(b * CHUNKS_ + c) * H_ + h], s);
    csum[gq][tid & 63] = s;
  }
  __syncthreads();
  if (tid < 64) {
    float s = csum[0][tid] + csum[1][tid] + csum[2][tid] + csum[3][tid];
    ctx[(size_t)b * H_ + j * 64 + tid] = s * invL;
  }

  // attn slice: 512 elems, reuse stored e = exp(sc - m_chunk)
  #pragma unroll
  for (int i = 0; i < 2; ++i) {
    const int s_ = j * 512 + tid + i * 256;
    attn[(size_t)b * S_ + s_] = scores_e[(size_t)b * S_ + s_] * wgt[s_ >> 6] * invL;
  }
}

extern "C" void kernel_launch(void* const* d_in, const int* in_sizes, int n_in,
                              void* d_out, int out_size, void* d_ws, size_t ws_size,
                              hipStream_t stream) {
  const float* enc   = (const float*)d_in[0];
  const float* dh    = (const float*)d_in[1];
  const float* W_enc = (const float*)d_in[2];
  const float* b_enc = (const float*)d_in[3];
  const float* W_dec = (const float*)d_in[4];
  const float* b_dec = (const float*)d_in[5];
  const float* W_e   = (const float*)d_in[6];
  // b_e (d_in[7]) dropped: softmax is shift-invariant, scores not an output.

  char* ws = (char*)d_ws;
  unsigned short* WT = (unsigned short*)(ws + WS_WT);
  float* bias   = (float*)(ws + WS_BIAS);
  float* scores = (float*)(ws + WS_SCORES);
  float* wsm    = (float*)(ws + WS_M);
  float* wsl    = (float*)(ws + WS_L);
  float* part   = (float*)(ws + WS_PART);

  float* ctx  = (float*)d_out;            // [32][512]
  float* attn = (float*)d_out + B_ * H_;  // [32][4096]

  prep_kernel<<<dim3(64), dim3(256), 0, stream>>>(dh, W_enc, b_enc, W_dec, b_dec, WT, bias);
  fused_kernel<<<dim3(2048), dim3(256), 0, stream>>>(enc, WT, bias, W_e, scores, wsm, wsl, part);
  finalize_kernel<<<dim3(256), dim3(256), 0, stream>>>(scores, wsm, wsl, part, ctx, attn);
}

// Round 5
// 402.009 us; speedup vs baseline: 1.0719x; 1.0051x over previous
//
#include <hip/hip_runtime.h>
#include <hip/hip_bf16.h>
#include <stdint.h>

// AdditiveAttention: B=32, S=4096, H=512, A=256
// d_out = [context: 32*512][attn: 32*4096]  (fp32)
//
// R9: A register ring deepened 6 -> 8 slots. At step k: issue A(k+8),
// stash-write A(k+2) (issued at k-6) -> 6 steps (~1000-1200 cyc) of
// HBM-latency slack (was 4 steps). Everything else identical to R8
// (write-ahead-2 stash, barrier after odd steps, grid 2048, 2 blocks/CU).

typedef __attribute__((ext_vector_type(4))) float f32x4;
typedef __attribute__((ext_vector_type(8))) short short8;

#define B_  32
#define S_  4096
#define H_  512
#define A_  256
#define CHUNKS_ 64   // 4096 / 64 rows per block

// ---- workspace layout (bytes) ----
#define WS_WT     0            // bf16 W_enc^T [256][512]   : 262144
#define WS_BIAS   262144       // fp32 [32][256]            : 32768
#define WS_SCORES 294912       // fp32 [32][4096] (exp vals): 524288
#define WS_M      819200       // fp32 [32][64]             : 8192
#define WS_L      827392       // fp32 [32][64]             : 8192
#define WS_PART   835584       // fp32 [32*64][512]         : 4194304

#define STRIDE_ 520            // stash row stride in shorts (1040 B, 16B-aligned)

static __device__ __forceinline__ short f2bf(float f) {
  union { float f; uint32_t u; } v; v.f = f;
  uint32_t r = (v.u + 0x7FFFu + ((v.u >> 16) & 1u)) >> 16;
  return (short)(uint16_t)r;
}
static __device__ __forceinline__ float bf2f(uint32_t lo16) {
  union { uint32_t u; float f; } v; v.u = lo16 << 16; return v.f;
}

// LDS-only barrier: drain lgkm (ds ops) but leave global loads in flight.
static __device__ __forceinline__ void lds_barrier() {
  asm volatile("s_waitcnt lgkmcnt(0)" ::: "memory");
  __builtin_amdgcn_s_barrier();
  asm volatile("" ::: "memory");
}

// ---------------- kernel 0: prep ------------------------------------------------
__global__ __launch_bounds__(256) void prep_kernel(
    const float* __restrict__ dh, const float* __restrict__ W_enc,
    const float* __restrict__ b_enc, const float* __restrict__ W_dec,
    const float* __restrict__ b_dec, unsigned short* __restrict__ WT,
    float* __restrict__ bias) {
  __shared__ float dh_s[512];
  __shared__ unsigned short tile[64 * 66];
  const int tid = threadIdx.x;
  if (blockIdx.x < 32) {
    const int b = blockIdx.x;
    dh_s[tid]       = dh[(size_t)b * H_ + tid];
    dh_s[tid + 256] = dh[(size_t)b * H_ + tid + 256];
    __syncthreads();
    float s[4] = {0.f, 0.f, 0.f, 0.f};
    for (int k = 0; k < H_; k += 32) {
      #pragma unroll
      for (int j = 0; j < 32; ++j)
        s[j & 3] = fmaf(dh_s[k + j], W_dec[(size_t)(k + j) * A_ + tid], s[j & 3]);
    }
    bias[b * A_ + tid] = s[0] + s[1] + s[2] + s[3] + b_enc[tid] + b_dec[tid];
  } else {
    const int t = blockIdx.x - 32;          // 0..31
    const int kt = t >> 2, nt2 = t & 3;     // k-tile (8), n-tile (4)
    #pragma unroll
    for (int i = 0; i < 16; ++i) {
      int idx = tid + i * 256;
      int kk = idx >> 6, nn = idx & 63;
      tile[kk * 66 + nn] =
          (unsigned short)f2bf(W_enc[(size_t)(kt * 64 + kk) * A_ + nt2 * 64 + nn]);
    }
    __syncthreads();
    #pragma unroll
    for (int i = 0; i < 16; ++i) {
      int idx = tid + i * 256;
      int nn = idx >> 6, kk = idx & 63;
      WT[(size_t)(nt2 * 64 + nn) * H_ + kt * 64 + kk] = tile[kk * 66 + nn];
    }
  }
}

// ---------------- kernel 1: fused -----------------------------------------------
// grid 2048 = 32 b x 64 chunks of 64 rows. 4 waves; wave w owns col-tiles
// nt_g = w*4..w*4+3 (cols w*64..+63), all 4 m-tiles (rows 0..63).
__global__ __launch_bounds__(256, 2) void fused_kernel(
    const float* __restrict__ enc, const unsigned short* __restrict__ WT,
    const float* __restrict__ bias, const float* __restrict__ We,
    float* __restrict__ scores, float* __restrict__ wsm,
    float* __restrict__ wsl, float* __restrict__ part) {
  __shared__ __align__(16) unsigned short stash[64 * STRIDE_];  // 66560 B
  __shared__ float s_ps[4][64];                                  // per-wave row partials
  __shared__ float s_e[64];

  const int tid = threadIdx.x, w = tid >> 6, lane = tid & 63;
  const int lm = lane & 15, lq = lane >> 4;
  const int b = blockIdx.x >> 6;
  const int chunk = blockIdx.x & 63;
  const int srow0 = blockIdx.x * 64;        // flat (b*S + s) row base

  f32x4 acc[4][4];
  #pragma unroll
  for (int mt = 0; mt < 4; ++mt)
    #pragma unroll
    for (int nt = 0; nt < 4; ++nt)
      acc[mt][nt] = (f32x4){0.f, 0.f, 0.f, 0.f};

  // ---- A staging addressing: thread t stages row tid>>2, k-span (tid&3)*8..+8
  const int arow = tid >> 2, akoff = (tid & 3) * 8;
  const float* aptr = enc + (size_t)(srow0 + arow) * H_ + akoff;
  unsigned short* swp = &stash[arow * STRIDE_ + akoff];

  // ---- B reg-ring addressing: lane's frag for nt_g = w*4+j:
  //      WT[(nt_g*16+lm)*512 + kstep*32 + lq*8]
  const unsigned short* bptr = WT + (size_t)((w * 4) * 16 + lm) * H_ + lq * 8;

  short8 Bring[3][4];
  float4 Ar[8][2];   // ring slot s holds A(k), k = s (mod 8); issue lead-8

  // ---- prologue: A(0),A(1) staged direct; ring slots 2..7 <- A(2)..A(7);
  //      B(0),B(1) into Bring ----
  float4 a0a = *(const float4*)aptr;
  float4 a0b = *(const float4*)(aptr + 4);
  float4 a1a = *(const float4*)(aptr + 32);
  float4 a1b = *(const float4*)(aptr + 36);
  #pragma unroll
  for (int p = 2; p < 8; ++p) {
    Ar[p][0] = *(const float4*)(aptr + p * 32);
    Ar[p][1] = *(const float4*)(aptr + p * 32 + 4);
  }
  #pragma unroll
  for (int j = 0; j < 4; ++j) {
    Bring[0][j] = *(const short8*)(bptr + (size_t)j * 16 * H_);        // B(0)
    Bring[1][j] = *(const short8*)(bptr + (size_t)j * 16 * H_ + 32);   // B(1)
  }
  {
    short8 sv;
    sv[0] = f2bf(a0a.x); sv[1] = f2bf(a0a.y); sv[2] = f2bf(a0a.z); sv[3] = f2bf(a0a.w);
    sv[4] = f2bf(a0b.x); sv[5] = f2bf(a0b.y); sv[6] = f2bf(a0b.z); sv[7] = f2bf(a0b.w);
    *(short8*)swp = sv;                     // stash region 0
    sv[0] = f2bf(a1a.x); sv[1] = f2bf(a1a.y); sv[2] = f2bf(a1a.z); sv[3] = f2bf(a1a.w);
    sv[4] = f2bf(a1b.x); sv[5] = f2bf(a1b.y); sv[6] = f2bf(a1b.z); sv[7] = f2bf(a1b.w);
    *(short8*)(swp + 32) = sv;              // stash region 1
  }
  lds_barrier();                            // regions 0,1 visible; loads in flight

  #pragma unroll
  for (int k = 0; k < 16; ++k) {
    // prefetch A(k+8) into ring slot k%8 (A(k) was consumed at step k-2)
    if (k < 8) {
      Ar[k][0] = *(const float4*)(aptr + (k + 8) * 32);
      Ar[k][1] = *(const float4*)(aptr + (k + 8) * 32 + 4);
    }
    // prefetch B(k+2) into ring slot (k+2)%3
    if (k < 14) {
      #pragma unroll
      for (int j = 0; j < 4; ++j)
        Bring[(k + 2) % 3][j] = *(const short8*)(bptr + (size_t)j * 16 * H_ + (k + 2) * 32);
    }
    // A fragments from stash region k; MFMA
    #pragma unroll
    for (int mt = 0; mt < 4; ++mt) {
      short8 af = *(const short8*)&stash[(mt * 16 + lm) * STRIDE_ + k * 32 + lq * 8];
      #pragma unroll
      for (int j = 0; j < 4; ++j)
        acc[mt][j] = __builtin_amdgcn_mfma_f32_16x16x32_bf16(af, Bring[k % 3][j], acc[mt][j], 0, 0, 0);
    }
    // write stash region k+2 from ring slot (k+2)%8 (issued at step k-6)
    if (k < 14) {
      float4 ca = Ar[(k + 2) & 7][0];
      float4 cb = Ar[(k + 2) & 7][1];
      short8 sv;
      sv[0] = f2bf(ca.x); sv[1] = f2bf(ca.y); sv[2] = f2bf(ca.z); sv[3] = f2bf(ca.w);
      sv[4] = f2bf(cb.x); sv[5] = f2bf(cb.y); sv[6] = f2bf(cb.z); sv[7] = f2bf(cb.w);
      *(short8*)(swp + (k + 2) * 32) = sv;
    }
    // barrier after odd steps only: write(region r)@step r-2 and read@step r
    // always have one barrier in between (same-parity write/read).
    if (k & 1) lds_barrier();
  }

  // ---- epilogue: per-wave partial score over its 64 cols ----
  // C/D: col = (w*4+j)*16 + lm, row(in mt) = lq*4 + r
  float psum[4][4] = {{0,0,0,0},{0,0,0,0},{0,0,0,0},{0,0,0,0}};
  #pragma unroll
  for (int j = 0; j < 4; ++j) {
    const int col = (w * 4 + j) * 16 + lm;
    const float dp = bias[b * A_ + col];
    const float wv = We[col];
    #pragma unroll
    for (int mt = 0; mt < 4; ++mt)
      #pragma unroll
      for (int r = 0; r < 4; ++r) {
        float x = acc[mt][j][r] + dp;
        float e = __expf(2.0f * x);
        float t = 1.0f - 2.0f * __builtin_amdgcn_rcpf(e + 1.0f);
        psum[mt][r] = fmaf(t, wv, psum[mt][r]);
      }
  }
  #pragma unroll
  for (int o = 1; o < 16; o <<= 1)
    #pragma unroll
    for (int mt = 0; mt < 4; ++mt)
      #pragma unroll
      for (int r = 0; r < 4; ++r)
        psum[mt][r] += __shfl_xor(psum[mt][r], o, 64);
  if (lm == 0) {
    #pragma unroll
    for (int mt = 0; mt < 4; ++mt)
      #pragma unroll
      for (int r = 0; r < 4; ++r)
        s_ps[w][mt * 16 + lq * 4 + r] = psum[mt][r];
  }
  lds_barrier();

  // ---- cross-wave sum, chunk softmax (wave 0); store e = exp(sc - m) ----
  if (tid < 64) {
    const float sc = s_ps[0][tid] + s_ps[1][tid] + s_ps[2][tid] + s_ps[3][tid];
    float m = sc;
    #pragma unroll
    for (int o = 1; o < 64; o <<= 1) m = fmaxf(m, __shfl_xor(m, o, 64));
    const float e = __expf(sc - m);
    float l = e;
    #pragma unroll
    for (int o = 1; o < 64; o <<= 1) l += __shfl_xor(l, o, 64);
    s_e[tid] = e;
    scores[srow0 + tid] = e;               // store exp value, not raw score
    if (tid == 0) {
      wsm[b * CHUNKS_ + chunk] = m;
      wsl[b * CHUNKS_ + chunk] = l;
    }
  }
  lds_barrier();

  // ---- phase 2: context partial from LDS stash (no global enc re-read) ----
  float cx0 = 0.f, cx1 = 0.f;
  #pragma unroll 8
  for (int row = 0; row < 64; ++row) {
    uint32_t pv = *(const uint32_t*)&stash[row * STRIDE_ + (tid << 1)];
    float wr = s_e[row];
    cx0 = fmaf(wr, bf2f(pv & 0xffffu), cx0);
    cx1 = fmaf(wr, bf2f(pv >> 16), cx1);
  }
  float2 o2; o2.x = cx0; o2.y = cx1;
  *(float2*)&part[(size_t)(b * CHUNKS_ + chunk) * H_ + (tid << 1)] = o2;
}

// ---------------- kernel 2: finalize --------------------------------------------
// grid 256 = 32 b x 8 slices. Each block redoes the tiny 64-chunk M/L reduce,
// then handles 64 ctx cols and 512 attn elems.
__global__ __launch_bounds__(256) void finalize_kernel(
    const float* __restrict__ scores_e, const float* __restrict__ wsm,
    const float* __restrict__ wsl, const float* __restrict__ part,
    float* __restrict__ ctx, float* __restrict__ attn) {
  __shared__ float wgt[CHUNKS_];
  __shared__ float s_inv;
  __shared__ float csum[4][64];
  const int b = blockIdx.x >> 3, j = blockIdx.x & 7;
  const int tid = threadIdx.x;
  if (tid < 64) {
    float mc = wsm[b * CHUNKS_ + tid];
    float lc = wsl[b * CHUNKS_ + tid];
    float M = mc;
    #pragma unroll
    for (int o = 1; o < 64; o <<= 1) M = fmaxf(M, __shfl_xor(M, o, 64));
    float wv = __expf(mc - M);
    float Lp = wv * lc;
    #pragma unroll
    for (int o = 1; o < 64; o <<= 1) Lp += __shfl_xor(Lp, o, 64);
    wgt[tid] = wv;
    if (tid == 0) s_inv = 1.0f / Lp;
  }
  __syncthreads();
  const float invL = s_inv;

  // ctx slice: h = j*64 + (tid&63); chunk-quarter g = tid>>6 sums 16 chunks
  {
    const int h = j * 64 + (tid & 63), gq = tid >> 6;
    float s = 0.f;
    #pragma unroll 4
    for (int c = gq * 16; c < gq * 16 + 16; ++c)
      s = fmaf(wgt[c], part[(size_t)(b * CHUNKS_ + c) * H_ + h], s);
    csum[gq][tid & 63] = s;
  }
  __syncthreads();
  if (tid < 64) {
    float s = csum[0][tid] + csum[1][tid] + csum[2][tid] + csum[3][tid];
    ctx[(size_t)b * H_ + j * 64 + tid] = s * invL;
  }

  // attn slice: 512 elems, reuse stored e = exp(sc - m_chunk)
  #pragma unroll
  for (int i = 0; i < 2; ++i) {
    const int s_ = j * 512 + tid + i * 256;
    attn[(size_t)b * S_ + s_] = scores_e[(size_t)b * S_ + s_] * wgt[s_ >> 6] * invL;
  }
}

extern "C" void kernel_launch(void* const* d_in, const int* in_sizes, int n_in,
                              void* d_out, int out_size, void* d_ws, size_t ws_size,
                              hipStream_t stream) {
  const float* enc   = (const float*)d_in[0];
  const float* dh    = (const float*)d_in[1];
  const float* W_enc = (const float*)d_in[2];
  const float* b_enc = (const float*)d_in[3];
  const float* W_dec = (const float*)d_in[4];
  const float* b_dec = (const float*)d_in[5];
  const float* W_e   = (const float*)d_in[6];
  // b_e (d_in[7]) dropped: softmax is shift-invariant, scores not an output.

  char* ws = (char*)d_ws;
  unsigned short* WT = (unsigned short*)(ws + WS_WT);
  float* bias   = (float*)(ws + WS_BIAS);
  float* scores = (float*)(ws + WS_SCORES);
  float* wsm    = (float*)(ws + WS_M);
  float* wsl    = (float*)(ws + WS_L);
  float* part   = (float*)(ws + WS_PART);

  float* ctx  = (float*)d_out;            // [32][512]
  float* attn = (float*)d_out + B_ * H_;  // [32][4096]

  prep_kernel<<<dim3(64), dim3(256), 0, stream>>>(dh, W_enc, b_enc, W_dec, b_dec, WT, bias);
  fused_kernel<<<dim3(2048), dim3(256), 0, stream>>>(enc, WT, bias, W_e, scores, wsm, wsl, part);
  finalize_kernel<<<dim3(256), dim3(256), 0, stream>>>(scores, wsm, wsl, part, ctx, attn);
}